// Round 5
// baseline (459.808 us; speedup 1.0000x reference)
//
#include <hip/hip_runtime.h>

// Problem constants
#define B_  2
#define S_  2048
#define D_  2048
#define H_  16
#define HD_ 128

// 1/sqrt(128) * log2(e): fold softmax scale AND exp->exp2 conversion into Q
#define QSCALE 0.1275174319003887f

typedef __attribute__((ext_vector_type(4))) float  f32x4;
typedef __attribute__((ext_vector_type(8))) short  short8;
typedef __attribute__((ext_vector_type(8))) __bf16 bf16x8;
typedef __attribute__((ext_vector_type(4))) float  floatv4;
typedef __attribute__((ext_vector_type(4))) unsigned short ushortv4;

// fp32 -> bf16 bits, round-to-nearest-even
__device__ inline unsigned short f2bf(float f) {
  unsigned int u = __builtin_bit_cast(unsigned int, f);
  u += 0x7fffu + ((u >> 16) & 1u);
  return (unsigned short)(u >> 16);
}

// async global->LDS, 16B per lane. lds must be wave-uniform base; data lands at base + lane*16.
__device__ inline void gld16(void* lds, const void* g) {
  __builtin_amdgcn_global_load_lds(
      (const __attribute__((address_space(1))) unsigned int*)g,
      (__attribute__((address_space(3))) unsigned int*)lds, 16, 0, 0);
}

__device__ inline bf16x8 lds_frag_b(const void* p) {
  return __builtin_bit_cast(bf16x8, *(const short8*)p);
}

// ---------------------------------------------------------------- fused converts (x + 4 weights)
__global__ void cvt_all(const float* __restrict__ x,
                        const float* __restrict__ w0, const float* __restrict__ w1,
                        const float* __restrict__ w2, const float* __restrict__ w3,
                        unsigned short* __restrict__ xb,
                        unsigned short* __restrict__ wb0, unsigned short* __restrict__ wb1,
                        unsigned short* __restrict__ wb2, unsigned short* __restrict__ wb3) {
  int i = blockIdx.x * 256 + threadIdx.x;   // quad index, total 6291456
  const float* s; unsigned short* d; int off;
  if (i < 2097152) { s = x; d = xb; off = i; }
  else {
    int j = i - 2097152;
    int r = j >> 20; off = j & 1048575;
    s = (r == 0) ? w0 : (r == 1) ? w1 : (r == 2) ? w2 : w3;
    d = (r == 0) ? wb0 : (r == 1) ? wb1 : (r == 2) ? wb2 : wb3;
  }
  floatv4 v = ((const floatv4*)s)[off];
  ushortv4 o;
  o.x = f2bf(v.x); o.y = f2bf(v.y); o.z = f2bf(v.z); o.w = f2bf(v.w);
  ((ushortv4*)d)[off] = o;
}

// ---------------------------------------------------------------- 4-phase GEMM (NT), BM=256 BN=128 BK=64, 8 waves.
// C[m][n] = sum_k A[m][k]*W[n][k] + bias[n].  K fixed = 2048 (32 K-tiles, 16 iters x 2 tiles).
// 16 MFMA per phase (was 8 in the 8-phase version: halves barrier+lgk-drain density per MFMA).
// Race ledger: stage each chunk >=1 barrier after its last ds_read phase:
//   buf0.A stage@F2 (read F1) | buf0.B @F3 (read F1/F2) | buf1.A @F4 (read F3) | buf1.B @F1-next (read F3/F4).
// Counted vmcnt(4)@F2 end: drains [buf1.A (prev F4) + buf1.B (this F1)] -> buf1 tile landed for F3.
// Counted vmcnt(4)@F4 end: drains [buf0.A (F2) + buf0.B (F3)] -> buf0 next tile landed for next F1.
// Never vmcnt(0) in-loop; tail restages identical bytes (benign).
// MODE 0: plain fp32 C (N=2048).  MODE 1: QKV fused epilogue - bias + RoPE (shfl_xor lane pairing),
// writes Qat/Kat bf16 (B,H,S,HD) + k_out/v_out fp32 directly; rope_kernel eliminated.
template<int MI0, int NJ0>
__device__ inline void quad_mm(f32x4 (&acc)[4][4], const bf16x8 (&af)[2][2], const bf16x8 (&bf)[2][2]) {
#pragma unroll
  for (int mi = 0; mi < 2; ++mi)
#pragma unroll
    for (int nj = 0; nj < 2; ++nj)
#pragma unroll
      for (int ks = 0; ks < 2; ++ks)
        acc[MI0 + mi][NJ0 + nj] =
            __builtin_amdgcn_mfma_f32_16x16x32_bf16(af[mi][ks], bf[nj][ks], acc[MI0 + mi][NJ0 + nj], 0, 0, 0);
}

// stage one 8KB chunk (64 rows x 128B): global row stride 4096B, per-thread offset thrOff pre-swizzled
__device__ inline void stage(char* ldsbuf, int chunk, const char* gtile, int w, long thrOff) {
  gld16(ldsbuf + chunk * 8192 + w * 1024, gtile + (long)chunk * 64 * 4096 + thrOff);
}

#define RDF(dst, buf, baserow)                                                          \
  do {                                                                                  \
    int _r0 = (baserow);                                                                \
    _Pragma("unroll") for (int _ii = 0; _ii < 2; ++_ii) {                               \
      int _row = _r0 + _ii * 16;                                                        \
      _Pragma("unroll") for (int _ks = 0; _ks < 2; ++_ks)                               \
          dst[_ii][_ks] = lds_frag_b((buf) + _row * 128 + ((_ks * 64 + quad * 16) ^ xsw)); \
    }                                                                                   \
  } while (0)

#define GBAR() __builtin_amdgcn_s_barrier()
#define LGK0()                                                 \
  do {                                                         \
    asm volatile("s_waitcnt lgkmcnt(0)" ::: "memory");         \
    __builtin_amdgcn_sched_barrier(0);                         \
  } while (0)

template<int MODE>
__global__ __launch_bounds__(512, 1)
void gemm8p(const unsigned short* __restrict__ A,
            const unsigned short* __restrict__ W,
            const float* __restrict__ b0, const float* __restrict__ b1, const float* __restrict__ b2,
            float* __restrict__ C0,
            unsigned short* __restrict__ Qat, unsigned short* __restrict__ Kat,
            float* __restrict__ k_out, float* __restrict__ v_out,
            const float* __restrict__ fc, const float* __restrict__ fs,
            int nbx) {
  __shared__ __attribute__((aligned(16))) char smem[98304];  // As0|As1 (32K each), Bs0|Bs1 (16K each)
  char* As0 = smem;
  char* As1 = smem + 32768;
  char* Bs0 = smem + 65536;
  char* Bs1 = smem + 81920;

  const int t = threadIdx.x, w = t >> 6, lane = t & 63;
  const int quad = lane >> 4, l16 = lane & 15;
  const int wm = (w >> 1) * 64, wn = (w & 1) * 64;   // 4M x 2N waves, 64x64 per wave
  const int xsw = (l16 & 7) << 4;

  // XCD-bijective block decode (grid divisible by 8): contiguous wg chunk per XCD
  const int nwg = gridDim.x, q8 = nwg >> 3;
  const int wg = ((int)blockIdx.x & 7) * q8 + ((int)blockIdx.x >> 3);
  const int by = wg / nbx, bx = wg % nbx;
  const int m0 = by * 256, n0 = bx * 128;

  const char* Agl = (const char*)A + (size_t)m0 * 4096;   // row stride K*2 = 4096 B
  const char* Wgl = (const char*)W + (size_t)n0 * 4096;
  const int sr = t >> 3;
  const long thrOff = (long)sr * 4096 + (((t & 7) * 16) ^ ((sr & 7) << 4));  // inverse-swizzled src

  // prologue: buf0 full (tile 0), buf1.A (tile 1); buf1.B staged at F1 of iter 0
#pragma unroll
  for (int c = 0; c < 4; ++c) stage(As0, c, Agl, w, thrOff);
#pragma unroll
  for (int c = 0; c < 2; ++c) stage(Bs0, c, Wgl, w, thrOff);
#pragma unroll
  for (int c = 0; c < 4; ++c) stage(As1, c, Agl + 128, w, thrOff);
  asm volatile("s_waitcnt vmcnt(4)" ::: "memory");   // tile0 landed; buf1.A(4) in flight
  GBAR();

  f32x4 acc[4][4] = {};

  for (int it = 0; it < 16; ++it) {
    int s0p = 2 * it + 2; if (s0p >= 32) s0p -= 2;   // tail: benign identical restage
    int s1p = 2 * it + 3; if (s1p >= 32) s1p -= 2;
    const char* gB1  = Wgl + (long)(2 * it + 1) * 128;   // buf1.B of CURRENT tile (never clamped)
    const char* gA0p = Agl + (long)s0p * 128;
    const char* gB0p = Wgl + (long)s0p * 128;
    const char* gA1p = Agl + (long)s1p * 128;
    bf16x8 a01[2][2], a23[2][2], b01[2][2], b23[2][2];

    // ---- F1: stage buf1.B; rd buf0 A01,A23,B01    | mfma Q(0,0)+Q(2,0) buf0
    stage(Bs1, 0, gB1, w, thrOff); stage(Bs1, 1, gB1, w, thrOff);
    RDF(a01, As0, wm + l16);
    RDF(a23, As0, wm + 32 + l16);
    RDF(b01, Bs0, wn + l16);
    GBAR(); LGK0();
    __builtin_amdgcn_s_setprio(1);
    quad_mm<0, 0>(acc, a01, b01); quad_mm<2, 0>(acc, a23, b01);
    __builtin_amdgcn_s_setprio(0);
    GBAR();
    // ---- F2: rd buf0.B23; stage buf0.A (next)     | mfma Q(0,2)+Q(2,2) buf0 | vmcnt(4): buf1 landed
    RDF(b23, Bs0, wn + 32 + l16);
    stage(As0, 0, gA0p, w, thrOff); stage(As0, 1, gA0p, w, thrOff);
    stage(As0, 2, gA0p, w, thrOff); stage(As0, 3, gA0p, w, thrOff);
    GBAR(); LGK0();
    __builtin_amdgcn_s_setprio(1);
    quad_mm<0, 2>(acc, a01, b23); quad_mm<2, 2>(acc, a23, b23);
    __builtin_amdgcn_s_setprio(0);
    asm volatile("s_waitcnt vmcnt(4)" ::: "memory");
    GBAR();
    // ---- F3: rd buf1 A01,A23,B01; stage buf0.B    | mfma Q(0,0)+Q(2,0) buf1
    RDF(a01, As1, wm + l16);
    RDF(a23, As1, wm + 32 + l16);
    RDF(b01, Bs1, wn + l16);
    stage(Bs0, 0, gB0p, w, thrOff); stage(Bs0, 1, gB0p, w, thrOff);
    GBAR(); LGK0();
    __builtin_amdgcn_s_setprio(1);
    quad_mm<0, 0>(acc, a01, b01); quad_mm<2, 0>(acc, a23, b01);
    __builtin_amdgcn_s_setprio(0);
    GBAR();
    // ---- F4: rd buf1.B23; stage buf1.A (next)     | mfma Q(0,2)+Q(2,2) buf1 | vmcnt(4): buf0 landed
    RDF(b23, Bs1, wn + 32 + l16);
    stage(As1, 0, gA1p, w, thrOff); stage(As1, 1, gA1p, w, thrOff);
    stage(As1, 2, gA1p, w, thrOff); stage(As1, 3, gA1p, w, thrOff);
    GBAR(); LGK0();
    __builtin_amdgcn_s_setprio(1);
    quad_mm<0, 2>(acc, a01, b23); quad_mm<2, 2>(acc, a23, b23);
    __builtin_amdgcn_s_setprio(0);
    asm volatile("s_waitcnt vmcnt(4)" ::: "memory");
    GBAR();
  }

  // drain tail restages before epilogue
  asm volatile("s_waitcnt vmcnt(0)" ::: "memory");

  // epilogue: C/D layout col=l16, row=quad*4+r
  if constexpr (MODE == 1) {
    // fused bias + RoPE. Paired columns (2i,2i+1) sit in adjacent lanes (l16 bit0) -> shfl_xor(1).
#pragma unroll
    for (int nj = 0; nj < 4; ++nj) {
      int col = n0 + wn + nj * 16 + l16;            // 0..6143
      int sel = col >> 11;                          // 0=Q 1=K 2=V (uniform across wave)
      int cc  = col & 2047;
      const float* bp = (sel == 0) ? b0 : (sel == 1) ? b1 : b2;
      float bv = bp[cc];
      int hh = cc >> 7, d = cc & 127, ii = d >> 1;
      float ssel = (d & 1) ? 1.f : -1.f;            // even: -sin, odd: +sin
#pragma unroll
      for (int mi = 0; mi < 4; ++mi)
#pragma unroll
        for (int r = 0; r < 4; ++r) {
          int row = m0 + wm + mi * 16 + quad * 4 + r;
          int s = row & 2047, bb = row >> 11;
          size_t dst = ((size_t)(bb * H_ + hh) * S_ + s) * HD_ + d;
          float v = acc[mi][nj][r] + bv;
          if (sel == 2) {
            v_out[dst] = v;
          } else {
            float pv = __shfl_xor(v, 1);            // partner column (same rows)
            float cs = fc[s * 64 + ii], sn = fs[s * 64 + ii];
            float o = v * cs + pv * sn * ssel;      // even: v*c - pv*s; odd: pv*s + v*c
            if (sel == 0) {
              Qat[dst] = f2bf(o * QSCALE);
            } else {
              Kat[dst] = f2bf(o);
              k_out[dst] = o;
            }
          }
        }
    }
  } else {
#pragma unroll
    for (int nj = 0; nj < 4; ++nj) {
      int col = n0 + wn + nj * 16 + l16;
      float bv = b0[col];
#pragma unroll
      for (int mi = 0; mi < 4; ++mi)
#pragma unroll
        for (int r = 0; r < 4; ++r) {
          int row = m0 + wm + mi * 16 + quad * 4 + r;
          C0[(size_t)row * 2048 + col] = acc[mi][nj][r] + bv;
        }
    }
  }
}

// ---------------------------------------------------------------- V: v_out (B,H,S,HD) fp32 -> Vt (B,H,HD,S) bf16
__global__ void vtrans_kernel(const float* __restrict__ Vsrc,
                              unsigned short* __restrict__ Vt) {
  __shared__ float tile[64][33];
  int t = threadIdx.x;
  int s0 = blockIdx.x * 64, d0 = blockIdx.y * 32, bh = blockIdx.z;
#pragma unroll
  for (int rr = 0; rr < 8; ++rr) {
    int sl = rr * 8 + (t >> 5), dl = t & 31;
    tile[sl][dl] = Vsrc[((size_t)(bh * S_ + s0 + sl)) * HD_ + d0 + dl];
  }
  __syncthreads();
#pragma unroll
  for (int rr = 0; rr < 8; ++rr) {
    int dl = rr * 4 + (t >> 6), sl = t & 63;
    Vt[((size_t)(bh * HD_ + d0 + dl)) * S_ + s0 + sl] = f2bf(tile[sl][dl]);
  }
}

// ---------------------------------------------------------------- causal flash attention
// 64 q-rows/block (16/wave), paired subtiles {qs, 31-qs} per block for perfect causal balance
// (33 k-tiles each). 512 blocks -> 2 blocks/CU. Ks/Vs/Ps XOR-swizzled ((row&7)<<4).
__global__ __launch_bounds__(256, 2)
void attn_kernel(const unsigned short* __restrict__ Qa,
                 const unsigned short* __restrict__ Ka,
                 const unsigned short* __restrict__ Vt,
                 unsigned short* __restrict__ Oa) {
  __shared__ __attribute__((aligned(16))) unsigned short Ks[2][64 * 128]; // 32 KB [key][d] swz
  __shared__ __attribute__((aligned(16))) unsigned short Vs[128 * 64];    // 16 KB  [d][key] swz
  __shared__ __attribute__((aligned(16))) unsigned short Ps[4][16 * 64];  //  8 KB  per-wave P swz
  const int t = threadIdx.x, w = t >> 6, lane = t & 63;
  const int quad = lane >> 4, l16 = lane & 15;
  const int bid = blockIdx.x;                 // 512 blocks
  const int bh = (bid & 7) + 8 * (bid >> 7);
  const int p  = (bid >> 3) & 15;             // pair index 0..15
  const int b = bh >> 4, h = bh & 15;
  const unsigned short* Qp = Qa + (size_t)bh * S_ * HD_;
  const unsigned short* Kp = Ka + (size_t)bh * S_ * HD_;
  const unsigned short* Vp = Vt + (size_t)bh * HD_ * S_;
  const float NEGINF = -__builtin_inff();

  for (int part = 0; part < 2; ++part) {
    const int qs = part ? (31 - p) : p;       // 64-row q-subtile index
    const int q0 = qs * 64;
    const int ntmax = qs;                     // k-tiles 0..qs (64 keys each)

    __syncthreads();   // prior part's LDS reads fully done before restage

    // stage K[0]: LDS[row][cb] = K[row][cb ^ ((row&7)<<4)]
#pragma unroll
    for (int j = 0; j < 4; ++j) {
      int o = (t + 256 * j) * 16;
      int row = o >> 8, cb = (o & 255) ^ ((row & 7) << 4);
      gld16((char*)Ks[0] + w * 1024 + j * 4096, (const char*)(Kp + (size_t)row * HD_) + cb);
    }
    // Q fragments: loop-invariant, straight from global (16B/lane)
    bf16x8 qf[4];
#pragma unroll
    for (int kk = 0; kk < 4; ++kk)
      qf[kk] = *(const bf16x8*)(Qp + (size_t)(q0 + w * 16 + l16) * HD_ + kk * 32 + quad * 8);

    float m_i[4], l_i[4];
#pragma unroll
    for (int r = 0; r < 4; ++r) { m_i[r] = NEGINF; l_i[r] = 0.f; }
    f32x4 oacc[8] = {};
    int c = 0;

    for (int nt = 0; nt <= ntmax; ++nt) {
      __syncthreads();   // K[c] resident; drains K prefetch issued last iter

      // early-issue V[nt]: consumed only after softmax (mid barrier). 128B rows, swizzled src.
#pragma unroll
      for (int j = 0; j < 4; ++j) {
        int o = (t + 256 * j) * 16;
        int vrow = o >> 7, vcb = (o & 127) ^ ((vrow & 7) << 4);
        gld16((char*)Vs + w * 1024 + j * 4096,
              (const char*)(Vp + (size_t)vrow * S_ + nt * 64) + vcb);
      }

      // --- S = Q K^T: wave's 16 q-rows x 64 keys (log2 domain)
      f32x4 sacc[4] = {};
      const char* Kc = (const char*)Ks[c];
#pragma unroll
      for (int j = 0; j < 4; ++j) {
        int krow = j * 16 + l16;
        const char* kbase = Kc + krow * 256;
        int ksw = (krow & 7) << 4;
#pragma unroll
        for (int kk = 0; kk < 4; ++kk) {
          bf16x8 kf = lds_frag_b(kbase + ((kk * 64 + quad * 16) ^ ksw));
          sacc[j] = __builtin_amdgcn_mfma_f32_16x16x32_bf16(qf[kk], kf, sacc[j], 0, 0, 0);
        }
      }

      // --- causal mask (diagonal tile only) + online softmax (exp2 domain)
      const bool dotail = (nt == ntmax);
      float rowmax[4], alpha[4], rowsum[4];
#pragma unroll
      for (int r = 0; r < 4; ++r) rowmax[r] = NEGINF;
#pragma unroll
      for (int j = 0; j < 4; ++j) {
        int scol = nt * 64 + j * 16 + l16;
#pragma unroll
        for (int r = 0; r < 4; ++r) {
          float v = sacc[j][r];
          if (dotail && scol > q0 + w * 16 + quad * 4 + r) v = NEGINF;
          sacc[j][r] = v;
          rowmax[r] = fmaxf(rowmax[r], v);
        }
      }
#pragma unroll
      for (int off = 1; off < 16; off <<= 1)
#pragma unroll
        for (int r = 0; r < 4; ++r)
          rowmax[r] = fmaxf(rowmax[r], __shfl_xor(rowmax[r], off));
#pragma unroll
      for (int r = 0; r < 4; ++r) {
        float mnew = fmaxf(m_i[r], rowmax[r]);
        alpha[r] = __builtin_amdgcn_exp2f(m_i[r] - mnew);   // first tile: exp2(-inf)=0
        m_i[r] = mnew;
        rowsum[r] = 0.f;
      }
#pragma unroll
      for (int j = 0; j < 4; ++j)
#pragma unroll
        for (int r = 0; r < 4; ++r) {
          float e = __builtin_amdgcn_exp2f(sacc[j][r] - m_i[r]);  // masked: exp2(-inf)=0
          sacc[j][r] = e;
          rowsum[r] += e;
        }
#pragma unroll
      for (int off = 1; off < 16; off <<= 1)
#pragma unroll
        for (int r = 0; r < 4; ++r)
          rowsum[r] += __shfl_xor(rowsum[r], off);
#pragma unroll
      for (int r = 0; r < 4; ++r) l_i[r] = l_i[r] * alpha[r] + rowsum[r];
#pragma unroll
      for (int f = 0; f < 8; ++f)
#pragma unroll
        for (int r = 0; r < 4; ++r) oacc[f][r] *= alpha[r];

      __syncthreads();   // V[nt] resident (drain covered by QK+softmax work)

      // prefetch K[nt+1] AFTER mid barrier: drained at NEXT top barrier (covered by PV)
      if (nt < ntmax) {
#pragma unroll
        for (int j = 0; j < 4; ++j) {
          int o = (t + 256 * j) * 16;
          int row = o >> 8, cb = (o & 255) ^ ((row & 7) << 4);
          gld16((char*)Ks[c ^ 1] + w * 1024 + j * 4096,
                (const char*)(Kp + (size_t)((nt + 1) * 64 + row) * HD_) + cb);
        }
      }

      // --- P: C-layout regs -> per-wave LDS (bf16, swizzled)
      char* Pw = (char*)&Ps[w][0];
#pragma unroll
      for (int j = 0; j < 4; ++j)
#pragma unroll
        for (int r = 0; r < 4; ++r) {
          int prow = quad * 4 + r;
          *(unsigned short*)(Pw + prow * 128 + ((2 * (j * 16 + l16)) ^ ((prow & 7) << 4))) = f2bf(sacc[j][r]);
        }
      asm volatile("s_waitcnt lgkmcnt(0)" ::: "memory");  // per-wave RAW on Ps

      // --- O += P V  (2 k-steps over 64 keys x 8 d-fragments)
      const char* Vb = (const char*)Vs;
      int psw = (l16 & 7) << 4;
#pragma unroll
      for (int s2 = 0; s2 < 2; ++s2) {
        bf16x8 pf = lds_frag_b(Pw + l16 * 128 + ((s2 * 64 + quad * 16) ^ psw));
#pragma unroll
        for (int f = 0; f < 8; ++f) {
          int vrow = f * 16 + l16;
          bf16x8 vf = lds_frag_b(Vb + vrow * 128 + ((s2 * 64 + quad * 16) ^ ((vrow & 7) << 4)));
          oacc[f] = __builtin_amdgcn_mfma_f32_16x16x32_bf16(pf, vf, oacc[f], 0, 0, 0);
        }
      }
      c ^= 1;
    }

    // epilogue: O / l -> bf16 (B,S,D)
    float invl[4];
#pragma unroll
    for (int r = 0; r < 4; ++r) invl[r] = 1.f / l_i[r];
#pragma unroll
    for (int f = 0; f < 8; ++f)
#pragma unroll
      for (int r = 0; r < 4; ++r) {
        int srow = q0 + w * 16 + quad * 4 + r;
        int d = f * 16 + l16;
        Oa[((size_t)(b * S_ + srow)) * D_ + h * HD_ + d] = f2bf(oacc[f][r] * invl[r]);
      }
  }
}

// ----------------------------------------------------------------
extern "C" void kernel_launch(void* const* d_in, const int* in_sizes, int n_in,
                              void* d_out, int out_size, void* d_ws, size_t ws_size,
                              hipStream_t stream) {
  const float* x    = (const float*)d_in[0];
  const float* wq_w = (const float*)d_in[1];
  const float* wq_b = (const float*)d_in[2];
  const float* wk_w = (const float*)d_in[3];
  const float* wk_b = (const float*)d_in[4];
  const float* wv_w = (const float*)d_in[5];
  const float* wv_b = (const float*)d_in[6];
  const float* wo_w = (const float*)d_in[7];
  const float* wo_b = (const float*)d_in[8];
  const float* fc   = (const float*)d_in[9];
  const float* fs   = (const float*)d_in[10];

  float* out = (float*)d_out;
  const size_t BSD = (size_t)B_ * S_ * D_;   // 8388608
  float* k_out = out + BSD;
  float* v_out = out + 2 * BSD;

  // workspace layout
  char* ws = (char*)d_ws;
  unsigned short* xb   = (unsigned short*)(ws);              // x bf16          16.78 MB
  unsigned short* wqb  = (unsigned short*)(ws + 16777216);   // wq bf16          8.39 MB (wq|wk|wv contiguous)
  unsigned short* wkb  = (unsigned short*)(ws + 25165824);
  unsigned short* wvb  = (unsigned short*)(ws + 33554432);
  unsigned short* wob  = (unsigned short*)(ws + 41943040);
  unsigned short* Qat  = (unsigned short*)(ws + 83886080);   // Q roped bf16 (B,H,S,HD), pre-scaled
  unsigned short* Kat  = (unsigned short*)(ws + 100663296);  // K roped bf16 (B,H,S,HD)
  unsigned short* Vt   = (unsigned short*)(ws + 117440512);  // V bf16 (B,H,HD,S)
  unsigned short* Ab   = (unsigned short*)(ws + 134217728);  // attn out bf16 (B,S,D)

  cvt_all<<<24576, 256, 0, stream>>>(x, wq_w, wk_w, wv_w, wo_w, xb, wqb, wkb, wvb, wob);

  // fused QKV GEMM + bias + RoPE epilogue (N=6144): 768 blocks = 3 exact CU rounds.
  // Writes Qat/Kat bf16 + k_out/v_out fp32 directly; no fp32 Q/K round-trip, no rope kernel.
  gemm8p<1><<<dim3(768), 512, 0, stream>>>(xb, wqb, wq_b, wk_b, wv_b,
                                           nullptr, Qat, Kat, k_out, v_out, fc, fs, 48);

  vtrans_kernel<<<dim3(32, 4, 32), 256, 0, stream>>>(v_out, Vt);
  attn_kernel<<<512, 256, 0, stream>>>(Qat, Kat, Vt, Ab);

  // output projection: 256 blocks = 1 exact CU round (13 args: 6 unused epilogue ptrs are null)
  gemm8p<0><<<dim3(256), 512, 0, stream>>>(Ab, wob, wo_b, nullptr, nullptr,
                                           out, nullptr, nullptr, nullptr, nullptr,
                                           nullptr, nullptr, 16);
}

// Round 6
// 438.916 us; speedup vs baseline: 1.0476x; 1.0476x over previous
//
#include <hip/hip_runtime.h>

// Problem constants
#define B_  2
#define S_  2048
#define D_  2048
#define H_  16
#define HD_ 128

// 1/sqrt(128) * log2(e): fold softmax scale AND exp->exp2 conversion into Q
#define QSCALE 0.1275174319003887f

typedef __attribute__((ext_vector_type(4))) float  f32x4;
typedef __attribute__((ext_vector_type(8))) short  short8;
typedef __attribute__((ext_vector_type(8))) __bf16 bf16x8;
typedef __attribute__((ext_vector_type(4))) float  floatv4;
typedef __attribute__((ext_vector_type(4))) unsigned short ushortv4;

// fp32 -> bf16 bits, round-to-nearest-even
__device__ inline unsigned short f2bf(float f) {
  unsigned int u = __builtin_bit_cast(unsigned int, f);
  u += 0x7fffu + ((u >> 16) & 1u);
  return (unsigned short)(u >> 16);
}

// async global->LDS, 16B per lane. lds must be wave-uniform base; data lands at base + lane*16.
__device__ inline void gld16(void* lds, const void* g) {
  __builtin_amdgcn_global_load_lds(
      (const __attribute__((address_space(1))) unsigned int*)g,
      (__attribute__((address_space(3))) unsigned int*)lds, 16, 0, 0);
}

__device__ inline bf16x8 lds_frag_b(const void* p) {
  return __builtin_bit_cast(bf16x8, *(const short8*)p);
}

// ---------------------------------------------------------------- fused converts (x + 4 weights)
__global__ void cvt_all(const float* __restrict__ x,
                        const float* __restrict__ w0, const float* __restrict__ w1,
                        const float* __restrict__ w2, const float* __restrict__ w3,
                        unsigned short* __restrict__ xb,
                        unsigned short* __restrict__ wb0, unsigned short* __restrict__ wb1,
                        unsigned short* __restrict__ wb2, unsigned short* __restrict__ wb3) {
  int i = blockIdx.x * 256 + threadIdx.x;   // quad index, total 6291456
  const float* s; unsigned short* d; int off;
  if (i < 2097152) { s = x; d = xb; off = i; }
  else {
    int j = i - 2097152;
    int r = j >> 20; off = j & 1048575;
    s = (r == 0) ? w0 : (r == 1) ? w1 : (r == 2) ? w2 : w3;
    d = (r == 0) ? wb0 : (r == 1) ? wb1 : (r == 2) ? wb2 : wb3;
  }
  floatv4 v = ((const floatv4*)s)[off];
  ushortv4 o;
  o.x = f2bf(v.x); o.y = f2bf(v.y); o.z = f2bf(v.z); o.w = f2bf(v.w);
  ((ushortv4*)d)[off] = o;
}

// ---------------------------------------------------------------- 4-phase GEMM (NT), BM=256 BN=128 BK=64, 8 waves.
// C[m][n] = sum_k A[m][k]*W[n][k] + bias[n].  K fixed = 2048 (32 K-tiles, 16 iters x 2 tiles).
// Race ledger: stage each chunk >=1 barrier after its last ds_read phase:
//   buf0.A stage@F2 (read F1) | buf0.B @F3 (read F1/F2) | buf1.A @F4 (read F3) | buf1.B @F1-next (read F3/F4).
// vmcnt(4)@F2 end drains [buf1.A(prev F4)+buf1.B(this F1)] -> buf1 landed for F3.
// vmcnt(4)@F4 end drains [buf0.A(F2)+buf0.B(F3)] -> buf0 next tile landed for next F1.
// Never vmcnt(0) in-loop; tail restages identical bytes (benign).
// MODE 0: plain fp32 C (N=2048).
// MODE 1: QKV - coalesced fp32 stores: Q->CQ (B,S,D), K->CK (B,S,D), V->v_out (B,H,S,HD) direct.
//         (R5's fused-RoPE epilogue reverted: 2B scattered stores caused +37MB RMW write traffic.)
template<int MI0, int NJ0>
__device__ inline void quad_mm(f32x4 (&acc)[4][4], const bf16x8 (&af)[2][2], const bf16x8 (&bf)[2][2]) {
#pragma unroll
  for (int mi = 0; mi < 2; ++mi)
#pragma unroll
    for (int nj = 0; nj < 2; ++nj)
#pragma unroll
      for (int ks = 0; ks < 2; ++ks)
        acc[MI0 + mi][NJ0 + nj] =
            __builtin_amdgcn_mfma_f32_16x16x32_bf16(af[mi][ks], bf[nj][ks], acc[MI0 + mi][NJ0 + nj], 0, 0, 0);
}

// stage one 8KB chunk (64 rows x 128B): global row stride 4096B, per-thread offset thrOff pre-swizzled
__device__ inline void stage(char* ldsbuf, int chunk, const char* gtile, int w, long thrOff) {
  gld16(ldsbuf + chunk * 8192 + w * 1024, gtile + (long)chunk * 64 * 4096 + thrOff);
}

#define RDF(dst, buf, baserow)                                                          \
  do {                                                                                  \
    int _r0 = (baserow);                                                                \
    _Pragma("unroll") for (int _ii = 0; _ii < 2; ++_ii) {                               \
      int _row = _r0 + _ii * 16;                                                        \
      _Pragma("unroll") for (int _ks = 0; _ks < 2; ++_ks)                               \
          dst[_ii][_ks] = lds_frag_b((buf) + _row * 128 + ((_ks * 64 + quad * 16) ^ xsw)); \
    }                                                                                   \
  } while (0)

#define GBAR() __builtin_amdgcn_s_barrier()
#define LGK0()                                                 \
  do {                                                         \
    asm volatile("s_waitcnt lgkmcnt(0)" ::: "memory");         \
    __builtin_amdgcn_sched_barrier(0);                         \
  } while (0)

template<int MODE>
__global__ __launch_bounds__(512, 1)
void gemm8p(const unsigned short* __restrict__ A,
            const unsigned short* __restrict__ W,
            const float* __restrict__ b0, const float* __restrict__ b1, const float* __restrict__ b2,
            float* __restrict__ CQ,      // MODE0: C. MODE1: Q fp32 (B,S,D)
            float* __restrict__ CK,      // MODE1: K fp32 (B,S,D)
            float* __restrict__ v_out,   // MODE1: V fp32 (B,H,S,HD)
            int nbx) {
  __shared__ __attribute__((aligned(16))) char smem[98304];  // As0|As1 (32K each), Bs0|Bs1 (16K each)
  char* As0 = smem;
  char* As1 = smem + 32768;
  char* Bs0 = smem + 65536;
  char* Bs1 = smem + 81920;

  const int t = threadIdx.x, w = t >> 6, lane = t & 63;
  const int quad = lane >> 4, l16 = lane & 15;
  const int wm = (w >> 1) * 64, wn = (w & 1) * 64;   // 4M x 2N waves, 64x64 per wave
  const int xsw = (l16 & 7) << 4;

  // XCD-bijective block decode (grid divisible by 8): contiguous wg chunk per XCD
  const int nwg = gridDim.x, q8 = nwg >> 3;
  const int wg = ((int)blockIdx.x & 7) * q8 + ((int)blockIdx.x >> 3);
  const int by = wg / nbx, bx = wg % nbx;
  const int m0 = by * 256, n0 = bx * 128;

  const char* Agl = (const char*)A + (size_t)m0 * 4096;   // row stride K*2 = 4096 B
  const char* Wgl = (const char*)W + (size_t)n0 * 4096;
  const int sr = t >> 3;
  const long thrOff = (long)sr * 4096 + (((t & 7) * 16) ^ ((sr & 7) << 4));  // inverse-swizzled src

  // prologue: buf0 full (tile 0), buf1.A (tile 1); buf1.B staged at F1 of iter 0
#pragma unroll
  for (int c = 0; c < 4; ++c) stage(As0, c, Agl, w, thrOff);
#pragma unroll
  for (int c = 0; c < 2; ++c) stage(Bs0, c, Wgl, w, thrOff);
#pragma unroll
  for (int c = 0; c < 4; ++c) stage(As1, c, Agl + 128, w, thrOff);
  asm volatile("s_waitcnt vmcnt(4)" ::: "memory");   // tile0 landed; buf1.A(4) in flight
  GBAR();

  f32x4 acc[4][4] = {};

  for (int it = 0; it < 16; ++it) {
    int s0p = 2 * it + 2; if (s0p >= 32) s0p -= 2;   // tail: benign identical restage
    int s1p = 2 * it + 3; if (s1p >= 32) s1p -= 2;
    const char* gB1  = Wgl + (long)(2 * it + 1) * 128;   // buf1.B of CURRENT tile (never clamped)
    const char* gA0p = Agl + (long)s0p * 128;
    const char* gB0p = Wgl + (long)s0p * 128;
    const char* gA1p = Agl + (long)s1p * 128;
    bf16x8 a01[2][2], a23[2][2], b01[2][2], b23[2][2];

    // ---- F1: stage buf1.B; rd buf0 A01,A23,B01    | mfma Q(0,0)+Q(2,0) buf0
    stage(Bs1, 0, gB1, w, thrOff); stage(Bs1, 1, gB1, w, thrOff);
    RDF(a01, As0, wm + l16);
    RDF(a23, As0, wm + 32 + l16);
    RDF(b01, Bs0, wn + l16);
    GBAR(); LGK0();
    __builtin_amdgcn_s_setprio(1);
    quad_mm<0, 0>(acc, a01, b01); quad_mm<2, 0>(acc, a23, b01);
    __builtin_amdgcn_s_setprio(0);
    GBAR();
    // ---- F2: rd buf0.B23; stage buf0.A (next)     | mfma Q(0,2)+Q(2,2) buf0 | vmcnt(4): buf1 landed
    RDF(b23, Bs0, wn + 32 + l16);
    stage(As0, 0, gA0p, w, thrOff); stage(As0, 1, gA0p, w, thrOff);
    stage(As0, 2, gA0p, w, thrOff); stage(As0, 3, gA0p, w, thrOff);
    GBAR(); LGK0();
    __builtin_amdgcn_s_setprio(1);
    quad_mm<0, 2>(acc, a01, b23); quad_mm<2, 2>(acc, a23, b23);
    __builtin_amdgcn_s_setprio(0);
    asm volatile("s_waitcnt vmcnt(4)" ::: "memory");
    GBAR();
    // ---- F3: rd buf1 A01,A23,B01; stage buf0.B    | mfma Q(0,0)+Q(2,0) buf1
    RDF(a01, As1, wm + l16);
    RDF(a23, As1, wm + 32 + l16);
    RDF(b01, Bs1, wn + l16);
    stage(Bs0, 0, gB0p, w, thrOff); stage(Bs0, 1, gB0p, w, thrOff);
    GBAR(); LGK0();
    __builtin_amdgcn_s_setprio(1);
    quad_mm<0, 0>(acc, a01, b01); quad_mm<2, 0>(acc, a23, b01);
    __builtin_amdgcn_s_setprio(0);
    GBAR();
    // ---- F4: rd buf1.B23; stage buf1.A (next)     | mfma Q(0,2)+Q(2,2) buf1 | vmcnt(4): buf0 landed
    RDF(b23, Bs1, wn + 32 + l16);
    stage(As1, 0, gA1p, w, thrOff); stage(As1, 1, gA1p, w, thrOff);
    stage(As1, 2, gA1p, w, thrOff); stage(As1, 3, gA1p, w, thrOff);
    GBAR(); LGK0();
    __builtin_amdgcn_s_setprio(1);
    quad_mm<0, 2>(acc, a01, b23); quad_mm<2, 2>(acc, a23, b23);
    __builtin_amdgcn_s_setprio(0);
    asm volatile("s_waitcnt vmcnt(4)" ::: "memory");
    GBAR();
  }

  // drain tail restages before epilogue
  asm volatile("s_waitcnt vmcnt(0)" ::: "memory");

  // epilogue: C/D layout col=l16, row=quad*4+r. All stores fp32, 64B-per-16-lane coalesced.
  if constexpr (MODE == 1) {
#pragma unroll
    for (int nj = 0; nj < 4; ++nj) {
      int col = n0 + wn + nj * 16 + l16;            // 0..6143
      int sel = col >> 11;                          // 0=Q 1=K 2=V (uniform across wave)
      int cc  = col & 2047;
      const float* bp = (sel == 0) ? b0 : (sel == 1) ? b1 : b2;
      float bv = bp[cc];
#pragma unroll
      for (int mi = 0; mi < 4; ++mi)
#pragma unroll
        for (int r = 0; r < 4; ++r) {
          int row = m0 + wm + mi * 16 + quad * 4 + r;
          float v = acc[mi][nj][r] + bv;
          if (sel == 0) {
            CQ[(size_t)row * 2048 + cc] = v;
          } else if (sel == 1) {
            CK[(size_t)row * 2048 + cc] = v;
          } else {
            int s = row & 2047, bb = row >> 11;
            int hh = cc >> 7, d = cc & 127;
            v_out[((size_t)(bb * H_ + hh) * S_ + s) * HD_ + d] = v;
          }
        }
    }
  } else {
#pragma unroll
    for (int nj = 0; nj < 4; ++nj) {
      int col = n0 + wn + nj * 16 + l16;
      float bv = b0[col];
#pragma unroll
      for (int mi = 0; mi < 4; ++mi)
#pragma unroll
        for (int r = 0; r < 4; ++r) {
          int row = m0 + wm + mi * 16 + quad * 4 + r;
          CQ[(size_t)row * 2048 + col] = acc[mi][nj][r] + bv;
        }
    }
  }
}

// ---------------------------------------------------------------- RoPE: Q,K (B,S,D) fp32 -> (B,H,S,HD)
// Qa gets scale*log2e folded in (softmax runs in exp2 domain); Ka/k_out are unscaled.
__global__ void rope_kernel(const float* __restrict__ Qbuf,
                            const float* __restrict__ Kbuf,
                            const float* __restrict__ fc,
                            const float* __restrict__ fs,
                            unsigned short* __restrict__ Qa,
                            unsigned short* __restrict__ Ka,
                            float* __restrict__ k_out) {
  int idx = blockIdx.x * 256 + threadIdx.x;   // (b:1, s:11, h:4, i:6)
  int i = idx & 63;
  int h = (idx >> 6) & (H_ - 1);
  int s = (idx >> 10) & (S_ - 1);
  int b = idx >> 21;
  size_t src = ((size_t)(b * S_ + s)) * D_ + h * HD_ + 2 * i;
  float2 q = *(const float2*)(Qbuf + src);
  float2 k = *(const float2*)(Kbuf + src);
  float c = fc[s * 64 + i], sn = fs[s * 64 + i];
  float qor = q.x * c - q.y * sn, qoi = q.x * sn + q.y * c;
  float kor = k.x * c - k.y * sn, koi = k.x * sn + k.y * c;
  size_t dst = ((size_t)((b * H_ + h) * S_ + s)) * HD_ + 2 * i;
  *(unsigned int*)(Qa + dst) = (unsigned int)f2bf(qor * QSCALE) | ((unsigned int)f2bf(qoi * QSCALE) << 16);
  *(unsigned int*)(Ka + dst) = (unsigned int)f2bf(kor) | ((unsigned int)f2bf(koi) << 16);
  *(float2*)(k_out + dst) = make_float2(kor, koi);
}

// ---------------------------------------------------------------- V: v_out (B,H,S,HD) fp32 -> Vt (B,H,HD,S) bf16
__global__ void vtrans_kernel(const float* __restrict__ Vsrc,
                              unsigned short* __restrict__ Vt) {
  __shared__ float tile[64][33];
  int t = threadIdx.x;
  int s0 = blockIdx.x * 64, d0 = blockIdx.y * 32, bh = blockIdx.z;
#pragma unroll
  for (int rr = 0; rr < 8; ++rr) {
    int sl = rr * 8 + (t >> 5), dl = t & 31;
    tile[sl][dl] = Vsrc[((size_t)(bh * S_ + s0 + sl)) * HD_ + d0 + dl];
  }
  __syncthreads();
#pragma unroll
  for (int rr = 0; rr < 8; ++rr) {
    int dl = rr * 4 + (t >> 6), sl = t & 63;
    Vt[((size_t)(bh * HD_ + d0 + dl)) * S_ + s0 + sl] = f2bf(tile[sl][dl]);
  }
}

// ---------------------------------------------------------------- causal flash attention
// 64 q-rows/block (16/wave), paired subtiles {qs, 31-qs} per block for perfect causal balance
// (33 k-tiles each). 512 blocks -> 2 blocks/CU. Ks/Vs/Ps XOR-swizzled ((row&7)<<4).
__global__ __launch_bounds__(256, 2)
void attn_kernel(const unsigned short* __restrict__ Qa,
                 const unsigned short* __restrict__ Ka,
                 const unsigned short* __restrict__ Vt,
                 unsigned short* __restrict__ Oa) {
  __shared__ __attribute__((aligned(16))) unsigned short Ks[2][64 * 128]; // 32 KB [key][d] swz
  __shared__ __attribute__((aligned(16))) unsigned short Vs[128 * 64];    // 16 KB  [d][key] swz
  __shared__ __attribute__((aligned(16))) unsigned short Ps[4][16 * 64];  //  8 KB  per-wave P swz
  const int t = threadIdx.x, w = t >> 6, lane = t & 63;
  const int quad = lane >> 4, l16 = lane & 15;
  const int bid = blockIdx.x;                 // 512 blocks
  const int bh = (bid & 7) + 8 * (bid >> 7);
  const int p  = (bid >> 3) & 15;             // pair index 0..15
  const int b = bh >> 4, h = bh & 15;
  const unsigned short* Qp = Qa + (size_t)bh * S_ * HD_;
  const unsigned short* Kp = Ka + (size_t)bh * S_ * HD_;
  const unsigned short* Vp = Vt + (size_t)bh * HD_ * S_;
  const float NEGINF = -__builtin_inff();

  for (int part = 0; part < 2; ++part) {
    const int qs = part ? (31 - p) : p;       // 64-row q-subtile index
    const int q0 = qs * 64;
    const int ntmax = qs;                     // k-tiles 0..qs (64 keys each)

    __syncthreads();   // prior part's LDS reads fully done before restage

    // stage K[0]: LDS[row][cb] = K[row][cb ^ ((row&7)<<4)]
#pragma unroll
    for (int j = 0; j < 4; ++j) {
      int o = (t + 256 * j) * 16;
      int row = o >> 8, cb = (o & 255) ^ ((row & 7) << 4);
      gld16((char*)Ks[0] + w * 1024 + j * 4096, (const char*)(Kp + (size_t)row * HD_) + cb);
    }
    // Q fragments: loop-invariant, straight from global (16B/lane)
    bf16x8 qf[4];
#pragma unroll
    for (int kk = 0; kk < 4; ++kk)
      qf[kk] = *(const bf16x8*)(Qp + (size_t)(q0 + w * 16 + l16) * HD_ + kk * 32 + quad * 8);

    float m_i[4], l_i[4];
#pragma unroll
    for (int r = 0; r < 4; ++r) { m_i[r] = NEGINF; l_i[r] = 0.f; }
    f32x4 oacc[8] = {};
    int c = 0;

    for (int nt = 0; nt <= ntmax; ++nt) {
      __syncthreads();   // K[c] resident; drains K prefetch issued last iter

      // early-issue V[nt]: consumed only after softmax (mid barrier). 128B rows, swizzled src.
#pragma unroll
      for (int j = 0; j < 4; ++j) {
        int o = (t + 256 * j) * 16;
        int vrow = o >> 7, vcb = (o & 127) ^ ((vrow & 7) << 4);
        gld16((char*)Vs + w * 1024 + j * 4096,
              (const char*)(Vp + (size_t)vrow * S_ + nt * 64) + vcb);
      }

      // --- S = Q K^T: wave's 16 q-rows x 64 keys (log2 domain)
      f32x4 sacc[4] = {};
      const char* Kc = (const char*)Ks[c];
#pragma unroll
      for (int j = 0; j < 4; ++j) {
        int krow = j * 16 + l16;
        const char* kbase = Kc + krow * 256;
        int ksw = (krow & 7) << 4;
#pragma unroll
        for (int kk = 0; kk < 4; ++kk) {
          bf16x8 kf = lds_frag_b(kbase + ((kk * 64 + quad * 16) ^ ksw));
          sacc[j] = __builtin_amdgcn_mfma_f32_16x16x32_bf16(qf[kk], kf, sacc[j], 0, 0, 0);
        }
      }

      // --- causal mask (diagonal tile only) + online softmax (exp2 domain)
      const bool dotail = (nt == ntmax);
      float rowmax[4], alpha[4], rowsum[4];
#pragma unroll
      for (int r = 0; r < 4; ++r) rowmax[r] = NEGINF;
#pragma unroll
      for (int j = 0; j < 4; ++j) {
        int scol = nt * 64 + j * 16 + l16;
#pragma unroll
        for (int r = 0; r < 4; ++r) {
          float v = sacc[j][r];
          if (dotail && scol > q0 + w * 16 + quad * 4 + r) v = NEGINF;
          sacc[j][r] = v;
          rowmax[r] = fmaxf(rowmax[r], v);
        }
      }
#pragma unroll
      for (int off = 1; off < 16; off <<= 1)
#pragma unroll
        for (int r = 0; r < 4; ++r)
          rowmax[r] = fmaxf(rowmax[r], __shfl_xor(rowmax[r], off));
#pragma unroll
      for (int r = 0; r < 4; ++r) {
        float mnew = fmaxf(m_i[r], rowmax[r]);
        alpha[r] = __builtin_amdgcn_exp2f(m_i[r] - mnew);   // first tile: exp2(-inf)=0
        m_i[r] = mnew;
        rowsum[r] = 0.f;
      }
#pragma unroll
      for (int j = 0; j < 4; ++j)
#pragma unroll
        for (int r = 0; r < 4; ++r) {
          float e = __builtin_amdgcn_exp2f(sacc[j][r] - m_i[r]);  // masked: exp2(-inf)=0
          sacc[j][r] = e;
          rowsum[r] += e;
        }
#pragma unroll
      for (int off = 1; off < 16; off <<= 1)
#pragma unroll
        for (int r = 0; r < 4; ++r)
          rowsum[r] += __shfl_xor(rowsum[r], off);
#pragma unroll
      for (int r = 0; r < 4; ++r) l_i[r] = l_i[r] * alpha[r] + rowsum[r];
#pragma unroll
      for (int f = 0; f < 8; ++f)
#pragma unroll
        for (int r = 0; r < 4; ++r) oacc[f][r] *= alpha[r];

      __syncthreads();   // V[nt] resident (drain covered by QK+softmax work)

      // prefetch K[nt+1] AFTER mid barrier: drained at NEXT top barrier (covered by PV)
      if (nt < ntmax) {
#pragma unroll
        for (int j = 0; j < 4; ++j) {
          int o = (t + 256 * j) * 16;
          int row = o >> 8, cb = (o & 255) ^ ((row & 7) << 4);
          gld16((char*)Ks[c ^ 1] + w * 1024 + j * 4096,
                (const char*)(Kp + (size_t)((nt + 1) * 64 + row) * HD_) + cb);
        }
      }

      // --- P: C-layout regs -> per-wave LDS (bf16, swizzled)
      char* Pw = (char*)&Ps[w][0];
#pragma unroll
      for (int j = 0; j < 4; ++j)
#pragma unroll
        for (int r = 0; r < 4; ++r) {
          int prow = quad * 4 + r;
          *(unsigned short*)(Pw + prow * 128 + ((2 * (j * 16 + l16)) ^ ((prow & 7) << 4))) = f2bf(sacc[j][r]);
        }
      asm volatile("s_waitcnt lgkmcnt(0)" ::: "memory");  // per-wave RAW on Ps

      // --- O += P V  (2 k-steps over 64 keys x 8 d-fragments)
      const char* Vb = (const char*)Vs;
      int psw = (l16 & 7) << 4;
#pragma unroll
      for (int s2 = 0; s2 < 2; ++s2) {
        bf16x8 pf = lds_frag_b(Pw + l16 * 128 + ((s2 * 64 + quad * 16) ^ psw));
#pragma unroll
        for (int f = 0; f < 8; ++f) {
          int vrow = f * 16 + l16;
          bf16x8 vf = lds_frag_b(Vb + vrow * 128 + ((s2 * 64 + quad * 16) ^ ((vrow & 7) << 4)));
          oacc[f] = __builtin_amdgcn_mfma_f32_16x16x32_bf16(pf, vf, oacc[f], 0, 0, 0);
        }
      }
      c ^= 1;
    }

    // epilogue: O / l -> bf16 (B,S,D)
    float invl[4];
#pragma unroll
    for (int r = 0; r < 4; ++r) invl[r] = 1.f / l_i[r];
#pragma unroll
    for (int f = 0; f < 8; ++f)
#pragma unroll
      for (int r = 0; r < 4; ++r) {
        int srow = q0 + w * 16 + quad * 4 + r;
        int d = f * 16 + l16;
        Oa[((size_t)(b * S_ + srow)) * D_ + h * HD_ + d] = f2bf(oacc[f][r] * invl[r]);
      }
  }
}

// ----------------------------------------------------------------
extern "C" void kernel_launch(void* const* d_in, const int* in_sizes, int n_in,
                              void* d_out, int out_size, void* d_ws, size_t ws_size,
                              hipStream_t stream) {
  const float* x    = (const float*)d_in[0];
  const float* wq_w = (const float*)d_in[1];
  const float* wq_b = (const float*)d_in[2];
  const float* wk_w = (const float*)d_in[3];
  const float* wk_b = (const float*)d_in[4];
  const float* wv_w = (const float*)d_in[5];
  const float* wv_b = (const float*)d_in[6];
  const float* wo_w = (const float*)d_in[7];
  const float* wo_b = (const float*)d_in[8];
  const float* fc   = (const float*)d_in[9];
  const float* fs   = (const float*)d_in[10];

  float* out = (float*)d_out;
  const size_t BSD = (size_t)B_ * S_ * D_;   // 8388608
  float* k_out = out + BSD;
  float* v_out = out + 2 * BSD;

  // workspace layout
  char* ws = (char*)d_ws;
  unsigned short* xb   = (unsigned short*)(ws);              // x bf16          16.78 MB
  unsigned short* wqb  = (unsigned short*)(ws + 16777216);   // wq bf16          8.39 MB (wq|wk|wv contiguous)
  unsigned short* wkb  = (unsigned short*)(ws + 25165824);
  unsigned short* wvb  = (unsigned short*)(ws + 33554432);
  unsigned short* wob  = (unsigned short*)(ws + 41943040);
  float*          Kbuf = (float*)(ws + 50331648);            // K fp32 (B,S,D)  33.55 MB
  unsigned short* Qat  = (unsigned short*)(ws + 83886080);   // Q roped bf16 (B,H,S,HD), pre-scaled
  unsigned short* Kat  = (unsigned short*)(ws + 100663296);  // K roped bf16 (B,H,S,HD)
  unsigned short* Vt   = (unsigned short*)(ws + 117440512);  // V bf16 (B,H,HD,S)
  unsigned short* Ab   = (unsigned short*)(ws + 134217728);  // attn out bf16 (B,S,D)

  // fp32 Q intermediate borrows d_out (overwritten by final out-projection)
  float* Qbuf = out;

  cvt_all<<<24576, 256, 0, stream>>>(x, wq_w, wk_w, wv_w, wo_w, xb, wqb, wkb, wvb, wob);

  // fused QKV GEMM (N=6144): 768 blocks = 3 exact CU rounds.
  // Q->Qbuf fp32, K->Kbuf fp32 (coalesced (B,S,D)); V->v_out fp32 (B,H,S,HD) direct.
  gemm8p<1><<<dim3(768), 512, 0, stream>>>(xb, wqb, wq_b, wk_b, wv_b,
                                           Qbuf, Kbuf, v_out, 48);

  rope_kernel<<<16384, 256, 0, stream>>>(Qbuf, Kbuf, fc, fs, Qat, Kat, k_out);
  vtrans_kernel<<<dim3(32, 4, 32), 256, 0, stream>>>(v_out, Vt);
  attn_kernel<<<512, 256, 0, stream>>>(Qat, Kat, Vt, Ab);

  // output projection: 256 blocks = 1 exact CU round
  gemm8p<0><<<dim3(256), 512, 0, stream>>>(Ab, wob, wo_b, nullptr, nullptr,
                                           out, nullptr, nullptr, 16);
}